// Round 1
// baseline (345.319 us; speedup 1.0000x reference)
//
#include <hip/hip_runtime.h>

#define SIDE 96
#define NN 9216            // SIDE*SIDE
#define BATCH 32

__device__ __forceinline__ float clamp01(float v) {
    // custom_sigmoid with THETA=0: where(x<0, 0, x) then min(,1)
    return fminf(fmaxf(v, 0.0f), 1.0f);
}

// xt[j*32 + b] = x[b*NN + j]
__global__ __launch_bounds__(256) void k_transpose(const float* __restrict__ x,
                                                   float* __restrict__ xt) {
    int idx = blockIdx.x * 256 + threadIdx.x;     // over NN*BATCH (exact multiple)
    int j = idx >> 5;
    int b = idx & 31;
    xt[idx] = x[(size_t)b * NN + j];
}

// Partial GEMM: part[s][j][b] = sum_{k in slice s} at[k][b] * W[k][j]
// One thread per output column j, 32 batch accumulators in registers.
// W reads are coalesced (lane -> consecutive columns); at reads are
// wave-uniform (scalarizable) float4 broadcasts.
__global__ __launch_bounds__(256, 2) void k_gemm_part(
    const float* __restrict__ W,      // [NN][NN] row-major (k-major)
    const float* __restrict__ at,     // [NN][BATCH]
    float* __restrict__ part,         // [S][NN][BATCH]
    int slice_len)
{
    const int ncolblk = NN / 256;     // 36
    int cb = blockIdx.x % ncolblk;
    int s  = blockIdx.x / ncolblk;
    int j  = cb * 256 + threadIdx.x;
    size_t k0 = (size_t)s * (size_t)slice_len;

    const float*  Wp = W + k0 * NN + j;
    const float4* ap = (const float4*)(at + k0 * BATCH);

    float acc[BATCH];
#pragma unroll
    for (int b = 0; b < BATCH; ++b) acc[b] = 0.0f;

    for (int kk = 0; kk < slice_len; kk += 8) {
        float w[8];
#pragma unroll
        for (int u = 0; u < 8; ++u) w[u] = Wp[(size_t)u * NN];
#pragma unroll
        for (int u = 0; u < 8; ++u) {
            const float4* a4 = ap + u * (BATCH / 4);
#pragma unroll
            for (int q = 0; q < 8; ++q) {
                float4 av = a4[q];
                acc[4*q+0] = fmaf(av.x, w[u], acc[4*q+0]);
                acc[4*q+1] = fmaf(av.y, w[u], acc[4*q+1]);
                acc[4*q+2] = fmaf(av.z, w[u], acc[4*q+2]);
                acc[4*q+3] = fmaf(av.w, w[u], acc[4*q+3]);
            }
        }
        Wp += 8 * (size_t)NN;
        ap += 8 * (BATCH / 4);
    }

    float4* pp = (float4*)(part + ((size_t)s * NN + (size_t)j) * BATCH);
#pragma unroll
    for (int q = 0; q < 8; ++q)
        pp[q] = make_float4(acc[4*q+0], acc[4*q+1], acc[4*q+2], acc[4*q+3]);
}

// aff_t[idx] = clamp01( sum_s part[s][idx] )
__global__ __launch_bounds__(256) void k_reduce_aff(const float* __restrict__ part,
                                                    float* __restrict__ aff_t,
                                                    int nslices) {
    int idx = blockIdx.x * 256 + threadIdx.x;
    float v = 0.0f;
    for (int s = 0; s < nslices; ++s)
        v += part[(size_t)s * NN * BATCH + idx];
    aff_t[idx] = clamp01(v);
}

// Fused epilogue: reduce inhibitory partials, sparse excitatory gather
// (13 compile-time-known offsets of the radius-2 circular mask), combine.
__global__ __launch_bounds__(256) void k_combine(
    const float* __restrict__ part,   // inhibitory partials [S][NN][BATCH]
    const float* __restrict__ aff_t,  // [NN][BATCH], already clamped
    const float* __restrict__ We,     // [NN][NN]
    float* __restrict__ out,          // [BATCH][NN]
    int nslices)
{
    int idx = blockIdx.x * 256 + threadIdx.x;
    int j = idx >> 5;
    int b = idx & 31;

    float inh = 0.0f;
    for (int s = 0; s < nslices; ++s)
        inh += part[(size_t)s * NN * BATCH + idx];
    inh = clamp01(inh);

    int mx = j / SIDE;
    int my = j - mx * SIDE;

    // offsets with dx*dx+dy*dy <= 4 (EXC_RADIUS=2): 13 taps
    const int dxs[13] = {-2,-1,-1,-1, 0, 0, 0, 0, 0, 1, 1, 1, 2};
    const int dys[13] = { 0,-1, 0, 1,-2,-1, 0, 1, 2,-1, 0, 1, 0};

    float exc = 0.0f;
#pragma unroll
    for (int t = 0; t < 13; ++t) {
        int x = mx + dxs[t];
        int y = my + dys[t];
        if ((unsigned)x < SIDE && (unsigned)y < SIDE) {
            int i = x * SIDE + y;
            float w = We[(size_t)i * NN + j];       // broadcast within half-wave
            exc = fmaf(aff_t[(size_t)i * BATCH + b], w, exc);
        }
    }
    exc = clamp01(exc);

    float a = aff_t[idx];
    out[(size_t)b * NN + j] = clamp01(a + 0.2f * exc - 0.4f * inh);
}

extern "C" void kernel_launch(void* const* d_in, const int* in_sizes, int n_in,
                              void* d_out, int out_size, void* d_ws, size_t ws_size,
                              hipStream_t stream) {
    const float* x  = (const float*)d_in[0];  // [32][9216]
    const float* Wr = (const float*)d_in[1];  // [9216][9216]
    const float* We = (const float*)d_in[2];  // [9216][9216] sparse (radius 2)
    const float* Wi = (const float*)d_in[3];  // [9216][9216]
    float* out = (float*)d_out;               // [32][9216]

    float* xt   = (float*)d_ws;                        // NN*BATCH floats
    float* afft = xt + (size_t)NN * BATCH;             // NN*BATCH floats
    float* part = afft + (size_t)NN * BATCH;           // S*NN*BATCH floats (shared
                                                       // by both GEMMs sequentially)

    // pick largest S (split-K factor) that fits the workspace
    size_t base_bytes = (size_t)NN * BATCH * 2 * sizeof(float);
    int S = 16;
    while (S > 1 && base_bytes + (size_t)S * NN * BATCH * sizeof(float) > ws_size)
        S >>= 1;
    int slice_len = NN / S;

    dim3 blk(256);
    dim3 grid_eb(NN * BATCH / 256);   // 1152
    dim3 grid_gm((NN / 256) * S);     // 36*S

    k_transpose <<<grid_eb, blk, 0, stream>>>(x, xt);
    k_gemm_part <<<grid_gm, blk, 0, stream>>>(Wr, xt, part, slice_len);
    k_reduce_aff<<<grid_eb, blk, 0, stream>>>(part, afft, S);
    k_gemm_part <<<grid_gm, blk, 0, stream>>>(Wi, afft, part, slice_len);
    k_combine   <<<grid_eb, blk, 0, stream>>>(part, afft, We, out, S);
}

// Round 2
// 289.346 us; speedup vs baseline: 1.1934x; 1.1934x over previous
//
#include <hip/hip_runtime.h>

#define SIDE 96
#define NN 9216            // SIDE*SIDE
#define BATCH 32
#define KC 64              // k-chunk staged in LDS per block

__device__ __forceinline__ float clamp01(float v) {
    // custom_sigmoid with THETA=0: where(x<0, 0, x) then min(,1)
    return fminf(fmaxf(v, 0.0f), 1.0f);
}

// xt[j*32 + b] = x[b*NN + j]
__global__ __launch_bounds__(256) void k_transpose(const float* __restrict__ x,
                                                   float* __restrict__ xt) {
    int idx = blockIdx.x * 256 + threadIdx.x;     // over NN*BATCH (exact multiple)
    int j = idx >> 5;
    int b = idx & 31;
    xt[idx] = x[(size_t)b * NN + j];
}

// Partial GEMM: part[s][j][b] = sum_{k in slice s} at[k][b] * W[k][j]
// One thread per output column j, 32 batch accumulators in registers.
// Activations staged in LDS per KC-chunk; W is the only global stream
// (coalesced 256B per wave-instruction).
__global__ __launch_bounds__(256, 4) void k_gemm_part(
    const float* __restrict__ W,      // [NN][NN] row-major (k-major)
    const float* __restrict__ at,     // [NN][BATCH]
    float* __restrict__ part,         // [S][NN][BATCH]
    int slice_len)
{
    __shared__ float sa[KC][BATCH];   // 8 KB

    const int ncolblk = NN / 256;     // 36
    int cb = blockIdx.x % ncolblk;
    int s  = blockIdx.x / ncolblk;
    int j  = cb * 256 + threadIdx.x;
    size_t k0 = (size_t)s * (size_t)slice_len;

    const float* Wp = W + k0 * NN + j;
    const float* ap = at + k0 * BATCH;

    float acc[BATCH];
#pragma unroll
    for (int b = 0; b < BATCH; ++b) acc[b] = 0.0f;

    for (int kk = 0; kk < slice_len; kk += KC) {
        __syncthreads();              // previous chunk's readers done
        {   // cooperative stage: KC*BATCH floats = 512 float4, 2 per thread
            const float4* src = (const float4*)(ap + (size_t)kk * BATCH);
            float4* dst = (float4*)sa;
            dst[threadIdx.x]       = src[threadIdx.x];
            dst[threadIdx.x + 256] = src[threadIdx.x + 256];
        }
        __syncthreads();

        const float* wcol = Wp + (size_t)kk * NN;
#pragma unroll 8
        for (int u = 0; u < KC; ++u) {
            float w = wcol[(size_t)u * NN];
            const float4* a4 = (const float4*)&sa[u][0];
#pragma unroll
            for (int q = 0; q < 8; ++q) {
                float4 av = a4[q];
                acc[4*q+0] = fmaf(av.x, w, acc[4*q+0]);
                acc[4*q+1] = fmaf(av.y, w, acc[4*q+1]);
                acc[4*q+2] = fmaf(av.z, w, acc[4*q+2]);
                acc[4*q+3] = fmaf(av.w, w, acc[4*q+3]);
            }
        }
    }

    float4* pp = (float4*)(part + ((size_t)s * NN + (size_t)j) * BATCH);
#pragma unroll
    for (int q = 0; q < 8; ++q)
        pp[q] = make_float4(acc[4*q+0], acc[4*q+1], acc[4*q+2], acc[4*q+3]);
}

// aff_t[idx] = clamp01( sum_s part[s][idx] )
__global__ __launch_bounds__(256) void k_reduce_aff(const float* __restrict__ part,
                                                    float* __restrict__ aff_t,
                                                    int nslices) {
    int idx = blockIdx.x * 256 + threadIdx.x;
    float v = 0.0f;
    for (int s = 0; s < nslices; ++s)
        v += part[(size_t)s * NN * BATCH + idx];
    aff_t[idx] = clamp01(v);
}

// Fused epilogue: reduce inhibitory partials, sparse excitatory gather
// (13 compile-time-known offsets of the radius-2 circular mask), combine.
__global__ __launch_bounds__(256) void k_combine(
    const float* __restrict__ part,   // inhibitory partials [S][NN][BATCH]
    const float* __restrict__ aff_t,  // [NN][BATCH], already clamped
    const float* __restrict__ We,     // [NN][NN]
    float* __restrict__ out,          // [BATCH][NN]
    int nslices)
{
    int idx = blockIdx.x * 256 + threadIdx.x;
    int j = idx >> 5;
    int b = idx & 31;

    float inh = 0.0f;
    for (int s = 0; s < nslices; ++s)
        inh += part[(size_t)s * NN * BATCH + idx];
    inh = clamp01(inh);

    int mx = j / SIDE;
    int my = j - mx * SIDE;

    // offsets with dx*dx+dy*dy <= 4 (EXC_RADIUS=2): 13 taps
    const int dxs[13] = {-2,-1,-1,-1, 0, 0, 0, 0, 0, 1, 1, 1, 2};
    const int dys[13] = { 0,-1, 0, 1,-2,-1, 0, 1, 2,-1, 0, 1, 0};

    float exc = 0.0f;
#pragma unroll
    for (int t = 0; t < 13; ++t) {
        int x = mx + dxs[t];
        int y = my + dys[t];
        if ((unsigned)x < SIDE && (unsigned)y < SIDE) {
            int i = x * SIDE + y;
            float w = We[(size_t)i * NN + j];       // broadcast within half-wave
            exc = fmaf(aff_t[(size_t)i * BATCH + b], w, exc);
        }
    }
    exc = clamp01(exc);

    float a = aff_t[idx];
    out[(size_t)b * NN + j] = clamp01(a + 0.2f * exc - 0.4f * inh);
}

extern "C" void kernel_launch(void* const* d_in, const int* in_sizes, int n_in,
                              void* d_out, int out_size, void* d_ws, size_t ws_size,
                              hipStream_t stream) {
    const float* x  = (const float*)d_in[0];  // [32][9216]
    const float* Wr = (const float*)d_in[1];  // [9216][9216]
    const float* We = (const float*)d_in[2];  // [9216][9216] sparse (radius 2)
    const float* Wi = (const float*)d_in[3];  // [9216][9216]
    float* out = (float*)d_out;               // [32][9216]

    float* xt   = (float*)d_ws;                        // NN*BATCH floats
    float* afft = xt + (size_t)NN * BATCH;             // NN*BATCH floats
    float* part = afft + (size_t)NN * BATCH;           // S*NN*BATCH floats (shared
                                                       // by both GEMMs sequentially)

    // Split-K factor: slice_len = NN/S must stay a multiple of KC=64.
    // S=36 -> slice 256 (4 chunks), 1296 blocks (~5/CU). Halving fallback
    // keeps divisibility (slice doubles).
    size_t base_bytes = (size_t)NN * BATCH * 2 * sizeof(float);
    int S = 36;
    while (S > 1 && base_bytes + (size_t)S * NN * BATCH * sizeof(float) > ws_size)
        S >>= 1;
    int slice_len = NN / S;

    dim3 blk(256);
    dim3 grid_eb(NN * BATCH / 256);   // 1152
    dim3 grid_gm((NN / 256) * S);     // 36*S

    k_transpose <<<grid_eb, blk, 0, stream>>>(x, xt);
    k_gemm_part <<<grid_gm, blk, 0, stream>>>(Wr, xt, part, slice_len);
    k_reduce_aff<<<grid_eb, blk, 0, stream>>>(part, afft, S);
    k_gemm_part <<<grid_gm, blk, 0, stream>>>(Wi, afft, part, slice_len);
    k_combine   <<<grid_eb, blk, 0, stream>>>(part, afft, We, out, S);
}